// Round 1
// baseline (904.392 us; speedup 1.0000x reference)
//
#include <hip/hip_runtime.h>

#define NN 20000      // nodes
#define NH 128        // hidden
#define NG 64         // graphs
#define NLAY 3
#define NCH 5         // 4 splits + main
#define GEPS 1e-5f
#define GSLOPE 0.01f

struct ZP {
  const float* A[NCH];
  const float* W[NCH];
  float* Y[NCH];
  float* Xo[NCH];
  const float* bias[NCH];
  const float* gw[NCH];
  const float* gb[NCH];
  const float* gms[NCH];
  int set[NCH];
  int colbase[NCH];
};

struct ES4 {
  const int* e[4];
  int cnt[4];
  int off[4];   // entry-array element offsets per edge set
};

// ---------------- setup kernels ----------------

__global__ void k_hist_batch(const int* __restrict__ batch, int* __restrict__ counts) {
  int i = blockIdx.x * 256 + threadIdx.x;
  if (i < NN) atomicAdd(&counts[batch[i]], 1);
}

__global__ void k_deg(ES4 es, int* __restrict__ deg) {
  int s = blockIdx.y;
  int i = blockIdx.x * 256 + threadIdx.x;
  int E = es.cnt[s];
  if (i < E) {
    int dst = es.e[s][E + i];
    atomicAdd(&deg[s * NN + dst], 1);
  }
}

__global__ void k_dinv(const int* __restrict__ deg, float* __restrict__ dinv) {
  int s = blockIdx.y;
  int i = blockIdx.x * 256 + threadIdx.x;
  if (i < NN) dinv[s * NN + i] = rsqrtf((float)deg[s * NN + i] + 1.0f);
}

// one block per edge set: exclusive scan of deg -> indptr (+ cursor copy)
__global__ void k_scan(const int* __restrict__ deg, int* __restrict__ indptr, int* __restrict__ cursor) {
  int s = blockIdx.x;
  const int* d = deg + s * NN;
  int* ip = indptr + s * (NN + 1);
  int* cu = cursor + s * (NN + 1);
  __shared__ int part[1024];
  int t = threadIdx.x;
  const int CH = (NN + 1023) / 1024;  // 20
  int base = t * CH;
  int sum = 0;
  for (int j = 0; j < CH; j++) { int idx = base + j; if (idx < NN) sum += d[idx]; }
  part[t] = sum;
  __syncthreads();
  for (int off = 1; off < 1024; off <<= 1) {
    int v = part[t];
    int u = (t >= off) ? part[t - off] : 0;
    __syncthreads();
    part[t] = v + u;
    __syncthreads();
  }
  int run = (t == 0) ? 0 : part[t - 1];
  for (int j = 0; j < CH; j++) {
    int idx = base + j;
    if (idx < NN) { ip[idx] = run; cu[idx] = run; run += d[idx]; }
  }
  if (t == 1023) { ip[NN] = run; cu[NN] = run; }
}

__global__ void k_fill(ES4 es, const float* __restrict__ dinv, int* __restrict__ cursor,
                       int2* __restrict__ ent) {
  int s = blockIdx.y;
  int i = blockIdx.x * 256 + threadIdx.x;
  int E = es.cnt[s];
  if (i >= E) return;
  int src = es.e[s][i];
  int dst = es.e[s][E + i];
  int pos = atomicAdd(&cursor[s * (NN + 1) + dst], 1);
  float c = dinv[s * NN + src] * dinv[s * NN + dst];
  ent[es.off[s] + pos] = make_int2(src, __float_as_int(c));
}

// ---------------- compute kernels ----------------

// C[z] = A[z] @ W[z] (+bias). 64x128 tile, BK=32, 256 thr, 8x4 per-thread.
__global__ __launch_bounds__(256) void k_gemm(ZP p, const float* __restrict__ bias) {
  int zi = blockIdx.y;
  const float* __restrict__ A = p.A[zi];
  const float* __restrict__ W = p.W[zi];
  float* __restrict__ C = p.Y[zi];
  __shared__ float As[32][64];   // [k][m]
  __shared__ float Bs[32][128];  // [k][n]
  int t = threadIdx.x;
  int tx = t & 31;   // col group: cols tx*4..tx*4+3
  int ty = t >> 5;   // row group: rows ty*8..ty*8+7
  int row0 = blockIdx.x * 64;
  float acc[8][4];
#pragma unroll
  for (int i = 0; i < 8; i++)
#pragma unroll
    for (int j = 0; j < 4; j++) acc[i][j] = 0.f;

  for (int kt = 0; kt < NH; kt += 32) {
#pragma unroll
    for (int pass = 0; pass < 2; pass++) {
      int r = pass * 32 + (t >> 3);
      int kk = (t & 7) * 4;
      int gr = row0 + r;
      float4 v = make_float4(0.f, 0.f, 0.f, 0.f);
      if (gr < NN) v = *(const float4*)(A + (size_t)gr * NH + kt + kk);
      As[kk + 0][r] = v.x; As[kk + 1][r] = v.y; As[kk + 2][r] = v.z; As[kk + 3][r] = v.w;
    }
#pragma unroll
    for (int pass = 0; pass < 4; pass++) {
      int idx = pass * 256 + t;
      int k = idx >> 5, n = (idx & 31) * 4;
      *(float4*)(&Bs[k][n]) = *(const float4*)(W + (size_t)(kt + k) * NH + n);
    }
    __syncthreads();
#pragma unroll
    for (int k = 0; k < 32; k++) {
      float4 a0 = *(const float4*)(&As[k][ty * 8]);
      float4 a1 = *(const float4*)(&As[k][ty * 8 + 4]);
      float4 b = *(const float4*)(&Bs[k][tx * 4]);
      float av[8] = {a0.x, a0.y, a0.z, a0.w, a1.x, a1.y, a1.z, a1.w};
#pragma unroll
      for (int i = 0; i < 8; i++) {
        acc[i][0] += av[i] * b.x;
        acc[i][1] += av[i] * b.y;
        acc[i][2] += av[i] * b.z;
        acc[i][3] += av[i] * b.w;
      }
    }
    __syncthreads();
  }
  float4 bb = make_float4(0.f, 0.f, 0.f, 0.f);
  if (bias) bb = *(const float4*)(bias + tx * 4);
#pragma unroll
  for (int i = 0; i < 8; i++) {
    int gr = row0 + ty * 8 + i;
    if (gr < NN) {
      float4 o = make_float4(acc[i][0] + bb.x, acc[i][1] + bb.y, acc[i][2] + bb.z, acc[i][3] + bb.w);
      *(float4*)(C + (size_t)gr * NH + tx * 4) = o;
    }
  }
}

// GCN aggregate: one wave per node, lane holds float2 of features.
__global__ __launch_bounds__(256) void k_agg(ZP p, const int* __restrict__ indptr,
                                             const int2* __restrict__ ent,
                                             const float* __restrict__ dinv, int4 entoff) {
  int zi = blockIdx.y;
  int wv = threadIdx.x >> 6, lane = threadIdx.x & 63;
  int node = blockIdx.x * 4 + wv;
  if (node >= NN) return;
  int s = p.set[zi];
  const int* ip = indptr + s * (NN + 1);
  int eb = (s == 0) ? entoff.x : ((s == 1) ? entoff.y : ((s == 2) ? entoff.z : entoff.w));
  const float* __restrict__ Y = p.Y[zi];
  int beg = ip[node], end = ip[node + 1];
  const int2* __restrict__ ev = ent + eb;
  float2 acc = make_float2(0.f, 0.f);
  for (int e = beg; e < end; e++) {
    int2 sc = ev[e];
    float c = __int_as_float(sc.y);
    float2 v = *(const float2*)(Y + (size_t)sc.x * NH + lane * 2);
    acc.x += c * v.x;
    acc.y += c * v.y;
  }
  float di = dinv[s * NN + node];
  float d2 = di * di;
  float2 sv = *(const float2*)(Y + (size_t)node * NH + lane * 2);
  float2 b2 = *(const float2*)(p.bias[zi] + lane * 2);
  float2 o = make_float2(acc.x + d2 * sv.x + b2.x, acc.y + d2 * sv.y + b2.y);
  *(float2*)(p.Xo[zi] + (size_t)node * NH + lane * 2) = o;
}

// per-(chain,graph,feature) sum and sum-of-squares, flush-on-graph-change
__global__ __launch_bounds__(256) void k_stats(ZP p, const int* __restrict__ batch,
                                               float* __restrict__ ssum, float* __restrict__ ssq) {
  int zi = blockIdx.y;
  const float* __restrict__ X = p.Xo[zi];
  int f = threadIdx.x & 127, rh = threadIdx.x >> 7;
  int r0 = blockIdx.x * 64;
  float s = 0.f, q = 0.f;
  int curg = -1;
  for (int i = rh; i < 64; i += 2) {
    int r = r0 + i;
    if (r >= NN) break;
    int g = batch[r];
    if (g != curg) {
      if (curg >= 0) {
        atomicAdd(&ssum[(zi * NG + curg) * NH + f], s);
        atomicAdd(&ssq[(zi * NG + curg) * NH + f], q);
      }
      curg = g; s = 0.f; q = 0.f;
    }
    float v = X[(size_t)r * NH + f];
    s += v;
    q += v * v;
  }
  if (curg >= 0) {
    atomicAdd(&ssum[(zi * NG + curg) * NH + f], s);
    atomicAdd(&ssq[(zi * NG + curg) * NH + f], q);
  }
}

// graph-norm + leaky relu in place, and accumulate per-graph sums into M[l]
__global__ __launch_bounds__(256) void k_apply(ZP p, const int* __restrict__ batch,
                                               const int* __restrict__ counts,
                                               const float* __restrict__ ssum,
                                               const float* __restrict__ ssq,
                                               float* __restrict__ Ml) {
  int zi = blockIdx.y;
  float* __restrict__ X = p.Xo[zi];
  int f = threadIdx.x & 127, rh = threadIdx.x >> 7;
  int r0 = blockIdx.x * 64;
  float w = p.gw[zi][f], b = p.gb[zi][f], ms = p.gms[zi][f];
  int col = p.colbase[zi] + f;
  float macc = 0.f;
  int curg = -1;
  float mean = 0.f, inv = 0.f;
  for (int i = rh; i < 64; i += 2) {
    int r = r0 + i;
    if (r >= NN) break;
    int g = batch[r];
    if (g != curg) {
      if (curg >= 0) atomicAdd(&Ml[curg * 640 + col], macc);
      macc = 0.f;
      curg = g;
      float cnt = fmaxf((float)counts[g], 1.f);
      float su = ssum[(zi * NG + g) * NH + f];
      float sq2 = ssq[(zi * NG + g) * NH + f];
      mean = su / cnt;
      float var = sq2 / cnt - (2.f * ms - ms * ms) * mean * mean;
      inv = rsqrtf(var + GEPS);
    }
    float v = X[(size_t)r * NH + f];
    float o = w * (v - ms * mean) * inv + b;
    o = (o >= 0.f) ? o : GSLOPE * o;
    X[(size_t)r * NH + f] = o;
    macc += o;
  }
  if (curg >= 0) atomicAdd(&Ml[curg * 640 + col], macc);
}

// out[g][f] = mean_l ( (M[l][g][:] @ mergeW[:,f]) / cnt[g] ) + mergeb[f]
__global__ __launch_bounds__(128) void k_final(const float* __restrict__ M,
                                               const float* __restrict__ mergeW,
                                               const float* __restrict__ mergeb,
                                               const int* __restrict__ counts,
                                               float* __restrict__ out) {
  int g = blockIdx.x;
  int f = threadIdx.x;  // 128
  __shared__ float mrow[640];
  float cnt = fmaxf((float)counts[g], 1.f);
  float acc = 0.f;
  for (int l = 0; l < NLAY; l++) {
    for (int i = f; i < 640; i += 128) mrow[i] = M[((size_t)l * NG + g) * 640 + i];
    __syncthreads();
    float s = 0.f;
    for (int k = 0; k < 640; k++) s += mrow[k] * mergeW[(size_t)k * NH + f];
    acc += s / cnt;
    __syncthreads();
  }
  out[(size_t)g * NH + f] = acc / 3.f + mergeb[f];
}

// ---------------- host ----------------

struct Offs {
  size_t counts, deg, M, stats, dinv, indptr, cursor, ent, h0;
  size_t xb[NCH], yb[NCH];
  size_t memset1_len, stats_len, total;
};

static size_t build_offs(Offs& o, int ngroup, int Etot) {
  size_t off = 0;
  auto alloc = [&](size_t bytes) -> size_t {
    off = (off + 255) & ~(size_t)255;
    size_t s = off;
    off += bytes;
    return s;
  };
  o.counts = alloc(NG * 4);
  o.deg = alloc((size_t)4 * NN * 4);
  o.M = alloc((size_t)NLAY * NG * 640 * 4);
  o.memset1_len = (o.M + (size_t)NLAY * NG * 640 * 4) - o.counts;
  o.stats = alloc((size_t)2 * NCH * NG * NH * 4);
  o.stats_len = (size_t)2 * NCH * NG * NH * 4;
  o.dinv = alloc((size_t)4 * NN * 4);
  o.indptr = alloc((size_t)4 * (NN + 1) * 4);
  o.cursor = alloc((size_t)4 * (NN + 1) * 4);
  o.ent = alloc((size_t)Etot * 8);
  o.h0 = alloc((size_t)NN * NH * 4);
  for (int i = 0; i < ngroup; i++) {
    o.xb[i] = alloc((size_t)NN * NH * 4);
    o.yb[i] = alloc((size_t)NN * NH * 4);
  }
  o.total = off;
  return off;
}

extern "C" void kernel_launch(void* const* d_in, const int* in_sizes, int n_in,
                              void* d_out, int out_size, void* d_ws, size_t ws_size,
                              hipStream_t stream) {
  if (n_in < 21) return;
  const float* x = (const float*)d_in[0];
  const float* embW = (const float*)d_in[1];
  const float* embb = (const float*)d_in[2];
  const float* mainW = (const float*)d_in[3];
  const float* mainb = (const float*)d_in[4];
  const float* maingw = (const float*)d_in[5];
  const float* maingb = (const float*)d_in[6];
  const float* maingms = (const float*)d_in[7];
  const float* locW = (const float*)d_in[8];
  const float* locb = (const float*)d_in[9];
  const float* locgw = (const float*)d_in[10];
  const float* locgb = (const float*)d_in[11];
  const float* locgms = (const float*)d_in[12];
  const float* mergeW = (const float*)d_in[13];
  const float* mergeb = (const float*)d_in[14];
  const int* edge_index = (const int*)d_in[15];
  // d_in[16] = edges0: permutation of edge_index under segment_sum -> reuse set 0
  const int* edges1 = (const int*)d_in[17];
  const int* edges2 = (const int*)d_in[18];
  const int* edges3 = (const int*)d_in[19];
  const int* batch = (const int*)d_in[20];

  int E0 = in_sizes[15] / 2;
  int E1 = in_sizes[17] / 2, E2 = in_sizes[18] / 2, E3 = in_sizes[19] / 2;
  int Etot = E0 + E1 + E2 + E3;
  int maxE = E0 > E1 ? E0 : E1;
  maxE = maxE > E2 ? maxE : E2;
  maxE = maxE > E3 ? maxE : E3;

  Offs o;
  int ngroup = NCH;
  if (build_offs(o, NCH, Etot) > ws_size) {
    ngroup = 1;
    if (build_offs(o, 1, Etot) > ws_size) return;  // not enough scratch; fail visibly
  }

  char* ws = (char*)d_ws;
  int* counts = (int*)(ws + o.counts);
  int* deg = (int*)(ws + o.deg);
  float* M = (float*)(ws + o.M);
  float* ssum = (float*)(ws + o.stats);
  float* ssq = ssum + (size_t)NCH * NG * NH;
  float* dinv = (float*)(ws + o.dinv);
  int* indptr = (int*)(ws + o.indptr);
  int* cursor = (int*)(ws + o.cursor);
  int2* ent = (int2*)(ws + o.ent);
  float* h0 = (float*)(ws + o.h0);
  float* xb[NCH];
  float* yb[NCH];
  for (int i = 0; i < ngroup; i++) {
    xb[i] = (float*)(ws + o.xb[i]);
    yb[i] = (float*)(ws + o.yb[i]);
  }

  ES4 es;
  es.e[0] = edge_index; es.e[1] = edges1; es.e[2] = edges2; es.e[3] = edges3;
  es.cnt[0] = E0; es.cnt[1] = E1; es.cnt[2] = E2; es.cnt[3] = E3;
  es.off[0] = 0; es.off[1] = E0; es.off[2] = E0 + E1; es.off[3] = E0 + E1 + E2;
  int4 entoff = make_int4(0, E0, E0 + E1, E0 + E1 + E2);

  // zero counts + deg + M (contiguous)
  hipMemsetAsync(ws + o.counts, 0, o.memset1_len, stream);
  k_hist_batch<<<(NN + 255) / 256, 256, 0, stream>>>(batch, counts);
  k_deg<<<dim3((maxE + 255) / 256, 4), 256, 0, stream>>>(es, deg);
  k_dinv<<<dim3((NN + 255) / 256, 4), 256, 0, stream>>>(deg, dinv);
  k_scan<<<4, 1024, 0, stream>>>(deg, indptr, cursor);
  k_fill<<<dim3((maxE + 255) / 256, 4), 256, 0, stream>>>(es, dinv, cursor, ent);

  // embedding: h0 = x @ embW + embb
  {
    ZP pe = {};
    pe.A[0] = x; pe.W[0] = embW; pe.Y[0] = h0;
    k_gemm<<<dim3((NN + 63) / 64, 1), 256, 0, stream>>>(pe, embb);
  }

  const int nrb = (NN + 63) / 64;  // 313
  for (int g0 = 0; g0 < NCH; g0 += ngroup) {
    int ng = (NCH - g0 < ngroup) ? (NCH - g0) : ngroup;
    for (int l = 0; l < NLAY; l++) {
      hipMemsetAsync(ws + o.stats, 0, o.stats_len, stream);
      ZP p = {};
      for (int zi = 0; zi < ng; zi++) {
        int c = g0 + zi;
        bool isMain = (c == 4);
        p.A[zi] = (l == 0) ? (const float*)h0 : (const float*)xb[zi];
        p.W[zi] = (isMain ? mainW : locW) + (size_t)l * NH * NH;
        p.Y[zi] = yb[zi];
        p.Xo[zi] = xb[zi];
        p.bias[zi] = (isMain ? mainb : locb) + (size_t)l * NH;
        p.gw[zi] = (isMain ? maingw : locgw) + (size_t)l * NH;
        p.gb[zi] = (isMain ? maingb : locgb) + (size_t)l * NH;
        p.gms[zi] = (isMain ? maingms : locgms) + (size_t)l * NH;
        p.set[zi] = (c == 0 || c == 4) ? 0 : c;
        p.colbase[zi] = isMain ? 512 : c * NH;
      }
      k_gemm<<<dim3(nrb, ng), 256, 0, stream>>>(p, (const float*)nullptr);
      k_agg<<<dim3(NN / 4, ng), 256, 0, stream>>>(p, indptr, ent, dinv, entoff);
      k_stats<<<dim3(nrb, ng), 256, 0, stream>>>(p, batch, ssum, ssq);
      k_apply<<<dim3(nrb, ng), 256, 0, stream>>>(p, batch, counts, ssum, ssq,
                                                 M + (size_t)l * NG * 640);
    }
  }

  k_final<<<NG, 128, 0, stream>>>(M, mergeW, mergeb, counts, (float*)d_out);
}

// Round 2
// 775.575 us; speedup vs baseline: 1.1661x; 1.1661x over previous
//
#include <hip/hip_runtime.h>

#define NN 20000      // nodes
#define NH 128        // hidden
#define NG 64         // graphs
#define NLAY 3
#define NCH 5         // 4 splits + main
#define GEPS 1e-5f
#define GSLOPE 0.01f

struct ZP {
  const float* A[NCH];
  const float* W[NCH];
  float* Y[NCH];
  float* Xo[NCH];
  const float* bias[NCH];
  const float* gw[NCH];
  const float* gb[NCH];
  const float* gms[NCH];
  int set[NCH];
  int colbase[NCH];
};

struct ES4 {
  const int* e[4];
  int cnt[4];
  int off[4];   // entry-array element offsets per edge set
};

// ---------------- setup kernels ----------------

// batch is sorted (np.sort in setup) -> counts via binary search, no atomics
__global__ void k_count(const int* __restrict__ batch, int* __restrict__ counts) {
  int g = threadIdx.x;  // 64 threads, one per graph
  if (g >= NG) return;
  auto lb = [&](int key) {
    int lo = 0, hi = NN;
    while (lo < hi) {
      int mid = (lo + hi) >> 1;
      if (batch[mid] < key) lo = mid + 1; else hi = mid;
    }
    return lo;
  };
  int a = lb(g), b = lb(g + 1);
  counts[g] = b - a;
}

__global__ void k_deg(ES4 es, int* __restrict__ deg) {
  int s = blockIdx.y;
  int i = blockIdx.x * 256 + threadIdx.x;
  int E = es.cnt[s];
  if (i < E) {
    int dst = es.e[s][E + i];
    atomicAdd(&deg[s * NN + dst], 1);
  }
}

__global__ void k_dinv(const int* __restrict__ deg, float* __restrict__ dinv) {
  int s = blockIdx.y;
  int i = blockIdx.x * 256 + threadIdx.x;
  if (i < NN) dinv[s * NN + i] = rsqrtf((float)deg[s * NN + i] + 1.0f);
}

// one block per edge set: exclusive scan of deg -> indptr (+ cursor copy)
__global__ void k_scan(const int* __restrict__ deg, int* __restrict__ indptr, int* __restrict__ cursor) {
  int s = blockIdx.x;
  const int* d = deg + s * NN;
  int* ip = indptr + s * (NN + 1);
  int* cu = cursor + s * (NN + 1);
  __shared__ int part[1024];
  int t = threadIdx.x;
  const int CH = (NN + 1023) / 1024;  // 20
  int base = t * CH;
  int sum = 0;
  for (int j = 0; j < CH; j++) { int idx = base + j; if (idx < NN) sum += d[idx]; }
  part[t] = sum;
  __syncthreads();
  for (int off = 1; off < 1024; off <<= 1) {
    int v = part[t];
    int u = (t >= off) ? part[t - off] : 0;
    __syncthreads();
    part[t] = v + u;
    __syncthreads();
  }
  int run = (t == 0) ? 0 : part[t - 1];
  for (int j = 0; j < CH; j++) {
    int idx = base + j;
    if (idx < NN) { ip[idx] = run; cu[idx] = run; run += d[idx]; }
  }
  if (t == 1023) { ip[NN] = run; cu[NN] = run; }
}

__global__ void k_fill(ES4 es, const float* __restrict__ dinv, int* __restrict__ cursor,
                       int2* __restrict__ ent) {
  int s = blockIdx.y;
  int i = blockIdx.x * 256 + threadIdx.x;
  int E = es.cnt[s];
  if (i >= E) return;
  int src = es.e[s][i];
  int dst = es.e[s][E + i];
  int pos = atomicAdd(&cursor[s * (NN + 1) + dst], 1);
  float c = dinv[s * NN + src] * dinv[s * NN + dst];
  ent[es.off[s] + pos] = make_int2(src, __float_as_int(c));
}

// ---------------- compute kernels ----------------

// C[z] = A[z] @ W[z] (+bias). 64x128 tile, BK=32, 256 thr, 8x4 per-thread.
__global__ __launch_bounds__(256) void k_gemm(ZP p, const float* __restrict__ bias) {
  int zi = blockIdx.y;
  const float* __restrict__ A = p.A[zi];
  const float* __restrict__ W = p.W[zi];
  float* __restrict__ C = p.Y[zi];
  __shared__ float As[32][64];   // [k][m]
  __shared__ float Bs[32][128];  // [k][n]
  int t = threadIdx.x;
  int tx = t & 31;   // col group: cols tx*4..tx*4+3
  int ty = t >> 5;   // row group: rows ty*8..ty*8+7
  int row0 = blockIdx.x * 64;
  float acc[8][4];
#pragma unroll
  for (int i = 0; i < 8; i++)
#pragma unroll
    for (int j = 0; j < 4; j++) acc[i][j] = 0.f;

  for (int kt = 0; kt < NH; kt += 32) {
#pragma unroll
    for (int pass = 0; pass < 2; pass++) {
      int r = pass * 32 + (t >> 3);
      int kk = (t & 7) * 4;
      int gr = row0 + r;
      float4 v = make_float4(0.f, 0.f, 0.f, 0.f);
      if (gr < NN) v = *(const float4*)(A + (size_t)gr * NH + kt + kk);
      As[kk + 0][r] = v.x; As[kk + 1][r] = v.y; As[kk + 2][r] = v.z; As[kk + 3][r] = v.w;
    }
#pragma unroll
    for (int pass = 0; pass < 4; pass++) {
      int idx = pass * 256 + t;
      int k = idx >> 5, n = (idx & 31) * 4;
      *(float4*)(&Bs[k][n]) = *(const float4*)(W + (size_t)(kt + k) * NH + n);
    }
    __syncthreads();
#pragma unroll
    for (int k = 0; k < 32; k++) {
      float4 a0 = *(const float4*)(&As[k][ty * 8]);
      float4 a1 = *(const float4*)(&As[k][ty * 8 + 4]);
      float4 b = *(const float4*)(&Bs[k][tx * 4]);
      float av[8] = {a0.x, a0.y, a0.z, a0.w, a1.x, a1.y, a1.z, a1.w};
#pragma unroll
      for (int i = 0; i < 8; i++) {
        acc[i][0] += av[i] * b.x;
        acc[i][1] += av[i] * b.y;
        acc[i][2] += av[i] * b.z;
        acc[i][3] += av[i] * b.w;
      }
    }
    __syncthreads();
  }
  float4 bb = make_float4(0.f, 0.f, 0.f, 0.f);
  if (bias) bb = *(const float4*)(bias + tx * 4);
#pragma unroll
  for (int i = 0; i < 8; i++) {
    int gr = row0 + ty * 8 + i;
    if (gr < NN) {
      float4 o = make_float4(acc[i][0] + bb.x, acc[i][1] + bb.y, acc[i][2] + bb.z, acc[i][3] + bb.w);
      *(float4*)(C + (size_t)gr * NH + tx * 4) = o;
    }
  }
}

// GCN aggregate: one wave per node, lane holds float2 of features.
__global__ __launch_bounds__(256) void k_agg(ZP p, const int* __restrict__ indptr,
                                             const int2* __restrict__ ent,
                                             const float* __restrict__ dinv, int4 entoff) {
  int zi = blockIdx.y;
  int wv = threadIdx.x >> 6, lane = threadIdx.x & 63;
  int node = blockIdx.x * 4 + wv;
  if (node >= NN) return;
  int s = p.set[zi];
  const int* ip = indptr + s * (NN + 1);
  int eb = (s == 0) ? entoff.x : ((s == 1) ? entoff.y : ((s == 2) ? entoff.z : entoff.w));
  const float* __restrict__ Y = p.Y[zi];
  int beg = ip[node], end = ip[node + 1];
  const int2* __restrict__ ev = ent + eb;
  float2 acc = make_float2(0.f, 0.f);
  for (int e = beg; e < end; e++) {
    int2 sc = ev[e];
    float c = __int_as_float(sc.y);
    float2 v = *(const float2*)(Y + (size_t)sc.x * NH + lane * 2);
    acc.x += c * v.x;
    acc.y += c * v.y;
  }
  float di = dinv[s * NN + node];
  float d2 = di * di;
  float2 sv = *(const float2*)(Y + (size_t)node * NH + lane * 2);
  float2 b2 = *(const float2*)(p.bias[zi] + lane * 2);
  float2 o = make_float2(acc.x + d2 * sv.x + b2.x, acc.y + d2 * sv.y + b2.y);
  *(float2*)(p.Xo[zi] + (size_t)node * NH + lane * 2) = o;
}

// per-(chain,graph,feature) sum and sum-of-squares, flush-on-graph-change
__global__ __launch_bounds__(256) void k_stats(ZP p, const int* __restrict__ batch,
                                               float* __restrict__ ssum, float* __restrict__ ssq) {
  int zi = blockIdx.y;
  const float* __restrict__ X = p.Xo[zi];
  int f = threadIdx.x & 127, rh = threadIdx.x >> 7;
  int r0 = blockIdx.x * 64;
  float s = 0.f, q = 0.f;
  int curg = -1;
  for (int i = rh; i < 64; i += 2) {
    int r = r0 + i;
    if (r >= NN) break;
    int g = batch[r];
    if (g != curg) {
      if (curg >= 0) {
        atomicAdd(&ssum[(zi * NG + curg) * NH + f], s);
        atomicAdd(&ssq[(zi * NG + curg) * NH + f], q);
      }
      curg = g; s = 0.f; q = 0.f;
    }
    float v = X[(size_t)r * NH + f];
    s += v;
    q += v * v;
  }
  if (curg >= 0) {
    atomicAdd(&ssum[(zi * NG + curg) * NH + f], s);
    atomicAdd(&ssq[(zi * NG + curg) * NH + f], q);
  }
}

// graph-norm + leaky relu in place, and accumulate per-graph sums into M[l]
__global__ __launch_bounds__(256) void k_apply(ZP p, const int* __restrict__ batch,
                                               const int* __restrict__ counts,
                                               const float* __restrict__ ssum,
                                               const float* __restrict__ ssq,
                                               float* __restrict__ Ml) {
  int zi = blockIdx.y;
  float* __restrict__ X = p.Xo[zi];
  int f = threadIdx.x & 127, rh = threadIdx.x >> 7;
  int r0 = blockIdx.x * 64;
  float w = p.gw[zi][f], b = p.gb[zi][f], ms = p.gms[zi][f];
  int col = p.colbase[zi] + f;
  float macc = 0.f;
  int curg = -1;
  float mean = 0.f, inv = 0.f;
  for (int i = rh; i < 64; i += 2) {
    int r = r0 + i;
    if (r >= NN) break;
    int g = batch[r];
    if (g != curg) {
      if (curg >= 0) atomicAdd(&Ml[curg * 640 + col], macc);
      macc = 0.f;
      curg = g;
      float cnt = fmaxf((float)counts[g], 1.f);
      float su = ssum[(zi * NG + g) * NH + f];
      float sq2 = ssq[(zi * NG + g) * NH + f];
      mean = su / cnt;
      float var = sq2 / cnt - (2.f * ms - ms * ms) * mean * mean;
      inv = rsqrtf(var + GEPS);
    }
    float v = X[(size_t)r * NH + f];
    float o = w * (v - ms * mean) * inv + b;
    o = (o >= 0.f) ? o : GSLOPE * o;
    X[(size_t)r * NH + f] = o;
    macc += o;
  }
  if (curg >= 0) atomicAdd(&Ml[curg * 640 + col], macc);
}

// T[l][g][f] = M[l][g][:] @ mergeW[:,f] ; K split across two halves of the block
__global__ __launch_bounds__(256) void k_merge(const float* __restrict__ M,
                                               const float* __restrict__ mergeW,
                                               float* __restrict__ T) {
  int g = blockIdx.x, l = blockIdx.y;
  int f = threadIdx.x & 127, h = threadIdx.x >> 7;  // h in {0,1}
  __shared__ float mrow[640];
  __shared__ float red[128];
  const float* Mr = M + ((size_t)l * NG + g) * 640;
  for (int i = threadIdx.x; i < 640; i += 256) mrow[i] = Mr[i];
  __syncthreads();
  float s = 0.f;
  int k0 = h * 320;
#pragma unroll 8
  for (int k = k0; k < k0 + 320; k++) s += mrow[k] * mergeW[(size_t)k * NH + f];
  if (h) red[f] = s;
  __syncthreads();
  if (!h) T[((size_t)l * NG + g) * NH + f] = s + red[f];
}

// out[g][f] = (T0+T1+T2)/(3*cnt) + mergeb
__global__ __launch_bounds__(128) void k_out(const float* __restrict__ T,
                                             const float* __restrict__ mergeb,
                                             const int* __restrict__ counts,
                                             float* __restrict__ out) {
  int g = blockIdx.x, f = threadIdx.x;
  float cnt = fmaxf((float)counts[g], 1.f);
  float s = T[((size_t)0 * NG + g) * NH + f] + T[((size_t)1 * NG + g) * NH + f] +
            T[((size_t)2 * NG + g) * NH + f];
  out[(size_t)g * NH + f] = s / (3.f * cnt) + mergeb[f];
}

// ---------------- host ----------------

struct Offs {
  size_t counts, deg, M, T, stats, dinv, indptr, cursor, ent, h0;
  size_t xb[NCH], yb[NCH];
  size_t memset1_off, memset1_len, stats_len, total;
};

static size_t build_offs(Offs& o, int ngroup, int Etot) {
  size_t off = 0;
  auto alloc = [&](size_t bytes) -> size_t {
    off = (off + 255) & ~(size_t)255;
    size_t s = off;
    off += bytes;
    return s;
  };
  o.counts = alloc(NG * 4);
  o.deg = alloc((size_t)4 * NN * 4);
  o.M = alloc((size_t)NLAY * NG * 640 * 4);
  o.memset1_off = o.deg;
  o.memset1_len = (o.M + (size_t)NLAY * NG * 640 * 4) - o.deg;
  o.T = alloc((size_t)NLAY * NG * NH * 4);
  o.stats = alloc((size_t)2 * NCH * NG * NH * 4);
  o.stats_len = (size_t)2 * NCH * NG * NH * 4;
  o.dinv = alloc((size_t)4 * NN * 4);
  o.indptr = alloc((size_t)4 * (NN + 1) * 4);
  o.cursor = alloc((size_t)4 * (NN + 1) * 4);
  o.ent = alloc((size_t)Etot * 8);
  o.h0 = alloc((size_t)NN * NH * 4);
  for (int i = 0; i < ngroup; i++) {
    o.xb[i] = alloc((size_t)NN * NH * 4);
    o.yb[i] = alloc((size_t)NN * NH * 4);
  }
  o.total = off;
  return off;
}

extern "C" void kernel_launch(void* const* d_in, const int* in_sizes, int n_in,
                              void* d_out, int out_size, void* d_ws, size_t ws_size,
                              hipStream_t stream) {
  if (n_in < 21) return;
  const float* x = (const float*)d_in[0];
  const float* embW = (const float*)d_in[1];
  const float* embb = (const float*)d_in[2];
  const float* mainW = (const float*)d_in[3];
  const float* mainb = (const float*)d_in[4];
  const float* maingw = (const float*)d_in[5];
  const float* maingb = (const float*)d_in[6];
  const float* maingms = (const float*)d_in[7];
  const float* locW = (const float*)d_in[8];
  const float* locb = (const float*)d_in[9];
  const float* locgw = (const float*)d_in[10];
  const float* locgb = (const float*)d_in[11];
  const float* locgms = (const float*)d_in[12];
  const float* mergeW = (const float*)d_in[13];
  const float* mergeb = (const float*)d_in[14];
  const int* edge_index = (const int*)d_in[15];
  // d_in[16] = edges0: permutation of edge_index under segment_sum -> reuse set 0
  const int* edges1 = (const int*)d_in[17];
  const int* edges2 = (const int*)d_in[18];
  const int* edges3 = (const int*)d_in[19];
  const int* batch = (const int*)d_in[20];

  int E0 = in_sizes[15] / 2;
  int E1 = in_sizes[17] / 2, E2 = in_sizes[18] / 2, E3 = in_sizes[19] / 2;
  int Etot = E0 + E1 + E2 + E3;
  int maxE = E0 > E1 ? E0 : E1;
  maxE = maxE > E2 ? maxE : E2;
  maxE = maxE > E3 ? maxE : E3;

  Offs o;
  int ngroup = NCH;
  if (build_offs(o, NCH, Etot) > ws_size) {
    ngroup = 1;
    if (build_offs(o, 1, Etot) > ws_size) return;  // not enough scratch; fail visibly
  }

  char* ws = (char*)d_ws;
  int* counts = (int*)(ws + o.counts);
  int* deg = (int*)(ws + o.deg);
  float* M = (float*)(ws + o.M);
  float* T = (float*)(ws + o.T);
  float* ssum = (float*)(ws + o.stats);
  float* ssq = ssum + (size_t)NCH * NG * NH;
  float* dinv = (float*)(ws + o.dinv);
  int* indptr = (int*)(ws + o.indptr);
  int* cursor = (int*)(ws + o.cursor);
  int2* ent = (int2*)(ws + o.ent);
  float* h0 = (float*)(ws + o.h0);
  float* xb[NCH];
  float* yb[NCH];
  for (int i = 0; i < ngroup; i++) {
    xb[i] = (float*)(ws + o.xb[i]);
    yb[i] = (float*)(ws + o.yb[i]);
  }

  ES4 es;
  es.e[0] = edge_index; es.e[1] = edges1; es.e[2] = edges2; es.e[3] = edges3;
  es.cnt[0] = E0; es.cnt[1] = E1; es.cnt[2] = E2; es.cnt[3] = E3;
  es.off[0] = 0; es.off[1] = E0; es.off[2] = E0 + E1; es.off[3] = E0 + E1 + E2;
  int4 entoff = make_int4(0, E0, E0 + E1, E0 + E1 + E2);

  // zero deg + M (contiguous)
  hipMemsetAsync(ws + o.memset1_off, 0, o.memset1_len, stream);
  k_count<<<1, 64, 0, stream>>>(batch, counts);
  k_deg<<<dim3((maxE + 255) / 256, 4), 256, 0, stream>>>(es, deg);
  k_dinv<<<dim3((NN + 255) / 256, 4), 256, 0, stream>>>(deg, dinv);
  k_scan<<<4, 1024, 0, stream>>>(deg, indptr, cursor);
  k_fill<<<dim3((maxE + 255) / 256, 4), 256, 0, stream>>>(es, dinv, cursor, ent);

  // embedding: h0 = x @ embW + embb
  {
    ZP pe = {};
    pe.A[0] = x; pe.W[0] = embW; pe.Y[0] = h0;
    k_gemm<<<dim3((NN + 63) / 64, 1), 256, 0, stream>>>(pe, embb);
  }

  const int nrb = (NN + 63) / 64;  // 313
  for (int g0 = 0; g0 < NCH; g0 += ngroup) {
    int ng = (NCH - g0 < ngroup) ? (NCH - g0) : ngroup;
    for (int l = 0; l < NLAY; l++) {
      hipMemsetAsync(ws + o.stats, 0, o.stats_len, stream);
      ZP p = {};
      for (int zi = 0; zi < ng; zi++) {
        int c = g0 + zi;
        bool isMain = (c == 4);
        p.A[zi] = (l == 0) ? (const float*)h0 : (const float*)xb[zi];
        p.W[zi] = (isMain ? mainW : locW) + (size_t)l * NH * NH;
        p.Y[zi] = yb[zi];
        p.Xo[zi] = xb[zi];
        p.bias[zi] = (isMain ? mainb : locb) + (size_t)l * NH;
        p.gw[zi] = (isMain ? maingw : locgw) + (size_t)l * NH;
        p.gb[zi] = (isMain ? maingb : locgb) + (size_t)l * NH;
        p.gms[zi] = (isMain ? maingms : locgms) + (size_t)l * NH;
        p.set[zi] = (c == 0 || c == 4) ? 0 : c;
        p.colbase[zi] = isMain ? 512 : c * NH;
      }
      if (ngroup == NCH && l == 0) {
        // chains 0..3 share A(h0) and W(locW[0]) at layer 0: compute once
        ZP pg = {};
        pg.A[0] = h0; pg.W[0] = locW; pg.Y[0] = yb[0];
        pg.A[1] = h0; pg.W[1] = mainW; pg.Y[1] = yb[4];
        k_gemm<<<dim3(nrb, 2), 256, 0, stream>>>(pg, (const float*)nullptr);
        // point split chains 1..3 at chain 0's GEMM output for aggregation
        p.Y[1] = yb[0]; p.Y[2] = yb[0]; p.Y[3] = yb[0];
      } else {
        k_gemm<<<dim3(nrb, ng), 256, 0, stream>>>(p, (const float*)nullptr);
      }
      k_agg<<<dim3(NN / 4, ng), 256, 0, stream>>>(p, indptr, ent, dinv, entoff);
      k_stats<<<dim3(nrb, ng), 256, 0, stream>>>(p, batch, ssum, ssq);
      k_apply<<<dim3(nrb, ng), 256, 0, stream>>>(p, batch, counts, ssum, ssq,
                                                 M + (size_t)l * NG * 640);
    }
  }

  k_merge<<<dim3(NG, NLAY), 256, 0, stream>>>(M, mergeW, T);
  k_out<<<NG, 128, 0, stream>>>(T, mergeb, counts, (float*)d_out);
}

// Round 3
// 543.058 us; speedup vs baseline: 1.6654x; 1.4282x over previous
//
#include <hip/hip_runtime.h>

#define NN 20000      // nodes
#define NNP 20032     // padded rows (64-row GEMM tiles read past NN)
#define NH 128        // hidden
#define NG 64         // graphs
#define NLAY 3
#define NCH 5         // 4 splits + main
#define GEPS 1e-5f
#define GSLOPE 0.01f

typedef unsigned short u16;
typedef unsigned int u32;
typedef __attribute__((ext_vector_type(8))) short short8;
typedef __attribute__((ext_vector_type(4))) float float4v;

__device__ __forceinline__ u16 f2bf(float f) {
  union { float f; u32 u; } v; v.f = f;
  u32 r = (v.u + 0x7fffu + ((v.u >> 16) & 1u)) >> 16;
  return (u16)r;
}
__device__ __forceinline__ float bf2f(u16 u) { return __uint_as_float((u32)u << 16); }

struct ZP {
  const u16* A[NCH];     // GEMM input (bf16, NNP rows)
  const u16* W[NCH];     // GEMM weight, bf16 transposed [N][K]
  u16* Y[NCH];           // GEMM output / gather source (bf16)
  u16* Xo[NCH];          // post-agg pre-norm (bf16)
  u16* Xn[NCH];          // post-norm, next layer's A (bf16, NNP rows)
  const float* bias[NCH];
  const float* gw[NCH];
  const float* gb[NCH];
  const float* gms[NCH];
  int set[NCH];
  int colbase[NCH];
};

struct ES4 {
  const int* e[4];
  int cnt[4];
  int off[4];
};

// ---------------- setup kernels ----------------

// batch is sorted -> counts via binary search, no atomics
__global__ void k_count(const int* __restrict__ batch, int* __restrict__ counts) {
  int g = threadIdx.x;
  if (g >= NG) return;
  auto lb = [&](int key) {
    int lo = 0, hi = NN;
    while (lo < hi) {
      int mid = (lo + hi) >> 1;
      if (batch[mid] < key) lo = mid + 1; else hi = mid;
    }
    return lo;
  };
  counts[g] = lb(g + 1) - lb(g);
}

__global__ void k_deg(ES4 es, int* __restrict__ deg) {
  int s = blockIdx.y;
  int i = blockIdx.x * 256 + threadIdx.x;
  int E = es.cnt[s];
  if (i < E) atomicAdd(&deg[s * NN + es.e[s][E + i]], 1);
}

__global__ void k_dinv(const int* __restrict__ deg, float* __restrict__ dinv) {
  int s = blockIdx.y;
  int i = blockIdx.x * 256 + threadIdx.x;
  if (i < NN) dinv[s * NN + i] = rsqrtf((float)deg[s * NN + i] + 1.0f);
}

__global__ void k_scan(const int* __restrict__ deg, int* __restrict__ indptr, int* __restrict__ cursor) {
  int s = blockIdx.x;
  const int* d = deg + s * NN;
  int* ip = indptr + s * (NN + 1);
  int* cu = cursor + s * (NN + 1);
  __shared__ int part[1024];
  int t = threadIdx.x;
  const int CH = (NN + 1023) / 1024;
  int base = t * CH;
  int sum = 0;
  for (int j = 0; j < CH; j++) { int idx = base + j; if (idx < NN) sum += d[idx]; }
  part[t] = sum;
  __syncthreads();
  for (int off = 1; off < 1024; off <<= 1) {
    int v = part[t];
    int u = (t >= off) ? part[t - off] : 0;
    __syncthreads();
    part[t] = v + u;
    __syncthreads();
  }
  int run = (t == 0) ? 0 : part[t - 1];
  for (int j = 0; j < CH; j++) {
    int idx = base + j;
    if (idx < NN) { ip[idx] = run; cu[idx] = run; run += d[idx]; }
  }
  if (t == 1023) { ip[NN] = run; cu[NN] = run; }
}

__global__ void k_fill(ES4 es, const float* __restrict__ dinv, int* __restrict__ cursor,
                       int2* __restrict__ ent) {
  int s = blockIdx.y;
  int i = blockIdx.x * 256 + threadIdx.x;
  int E = es.cnt[s];
  if (i >= E) return;
  int src = es.e[s][i];
  int dst = es.e[s][E + i];
  int pos = atomicAdd(&cursor[s * (NN + 1) + dst], 1);
  float c = dinv[s * NN + src] * dinv[s * NN + dst];
  ent[es.off[s] + pos] = make_int2(src, __float_as_int(c));
}

// weights: fp32 [K][N] -> bf16 transposed [N][K]; mats: 0=emb, 1-3=loc, 4-6=main
__global__ void k_prepw(const float* __restrict__ embW, const float* __restrict__ locW,
                        const float* __restrict__ mainW, u16* __restrict__ wt) {
  int mat = blockIdx.y;
  int n = blockIdx.x;
  int k = threadIdx.x;
  const float* W = (mat == 0) ? embW : ((mat <= 3) ? locW + (mat - 1) * NH * NH
                                                   : mainW + (mat - 4) * NH * NH);
  wt[(size_t)mat * NH * NH + n * NH + k] = f2bf(W[(size_t)k * NH + n]);
}

__global__ void k_cast(const float* __restrict__ x, u16* __restrict__ xb) {
  int i = (blockIdx.x * 256 + threadIdx.x) * 8;
  if (i >= NN * NH) return;
  float4 a = *(const float4*)(x + i);
  float4 b = *(const float4*)(x + i + 4);
  uint4 o;
  o.x = f2bf(a.x) | ((u32)f2bf(a.y) << 16);
  o.y = f2bf(a.z) | ((u32)f2bf(a.w) << 16);
  o.z = f2bf(b.x) | ((u32)f2bf(b.y) << 16);
  o.w = f2bf(b.z) | ((u32)f2bf(b.w) << 16);
  *(uint4*)(xb + i) = o;
}

// ---------------- compute kernels ----------------

// Y[z] = A[z] @ Wt[z]^T (+gbias). bf16 MFMA 16x16x32, 64-row tile, K=128 in LDS.
__global__ __launch_bounds__(256) void k_gemm_bf(ZP p, const float* __restrict__ gbias) {
  int zi = blockIdx.y;
  const u16* __restrict__ A = p.A[zi];
  const u16* __restrict__ Wt = p.W[zi];
  u16* __restrict__ Y = p.Y[zi];
  __shared__ u16 As[64][136];   // +8 pad: 2-way bank aliasing only
  __shared__ u16 Bs[128][136];
  int t = threadIdx.x;
  int row0 = blockIdx.x * 64;
  int c = t & 15, rs = t >> 4;
#pragma unroll
  for (int pass = 0; pass < 4; pass++) {
    int r = pass * 16 + rs;
    *(uint4*)(&As[r][c * 8]) = *(const uint4*)(A + (size_t)(row0 + r) * NH + c * 8);
  }
#pragma unroll
  for (int pass = 0; pass < 8; pass++) {
    int n = pass * 16 + rs;
    *(uint4*)(&Bs[n][c * 8]) = *(const uint4*)(Wt + (size_t)n * NH + c * 8);
  }
  __syncthreads();
  int lane = t & 63, w = t >> 6;
  int m16 = lane & 15, quad = lane >> 4;
  float4v acc[8];
#pragma unroll
  for (int i = 0; i < 8; i++) acc[i] = (float4v)(0.f);
#pragma unroll
  for (int kk = 0; kk < 4; kk++) {
    short8 av = *(const short8*)(&As[w * 16 + m16][kk * 32 + quad * 8]);
#pragma unroll
    for (int ct = 0; ct < 8; ct++) {
      short8 bv = *(const short8*)(&Bs[ct * 16 + m16][kk * 32 + quad * 8]);
      acc[ct] = __builtin_amdgcn_mfma_f32_16x16x32_bf16(av, bv, acc[ct], 0, 0, 0);
    }
  }
  __syncthreads();
  // epilogue: C/D layout col=lane&15, row=quad*4+reg -> LDS bounce -> 16B stores
#pragma unroll
  for (int ct = 0; ct < 8; ct++) {
    float bv = gbias ? gbias[ct * 16 + m16] : 0.f;
#pragma unroll
    for (int r = 0; r < 4; r++) {
      As[w * 16 + quad * 4 + r][ct * 16 + m16] = f2bf(acc[ct][r] + bv);
    }
  }
  __syncthreads();
#pragma unroll
  for (int pass = 0; pass < 4; pass++) {
    int r = pass * 16 + rs;
    int gr = row0 + r;
    if (gr < NN) *(uint4*)(Y + (size_t)gr * NH + c * 8) = *(const uint4*)(&As[r][c * 8]);
  }
}

// GCN aggregate: wave per node; 4 edge-groups x 16 lanes x 8 bf16 (16B gathers).
__global__ __launch_bounds__(256) void k_agg(ZP p, const int* __restrict__ indptr,
                                             const int2* __restrict__ ent,
                                             const float* __restrict__ dinv, int4 entoff) {
  int zi = blockIdx.y;
  int wv = threadIdx.x >> 6, lane = threadIdx.x & 63;
  int node = blockIdx.x * 4 + wv;
  if (node >= NN) return;
  int s = p.set[zi];
  const int* ip = indptr + s * (NN + 1);
  int eb = (s == 0) ? entoff.x : ((s == 1) ? entoff.y : ((s == 2) ? entoff.z : entoff.w));
  const u16* __restrict__ Y = p.Y[zi];
  int beg = ip[node], end = ip[node + 1];
  const int2* __restrict__ ev = ent + eb;
  int g = lane >> 4;
  int fo = (lane & 15) * 8;
  float acc[8] = {0.f, 0.f, 0.f, 0.f, 0.f, 0.f, 0.f, 0.f};
  for (int e = beg + g; e < end; e += 4) {
    int2 sc = ev[e];
    float cf = __int_as_float(sc.y);
    uint4 v = *(const uint4*)(Y + (size_t)sc.x * NH + fo);
    acc[0] += cf * __uint_as_float(v.x << 16);
    acc[1] += cf * __uint_as_float(v.x & 0xffff0000u);
    acc[2] += cf * __uint_as_float(v.y << 16);
    acc[3] += cf * __uint_as_float(v.y & 0xffff0000u);
    acc[4] += cf * __uint_as_float(v.z << 16);
    acc[5] += cf * __uint_as_float(v.z & 0xffff0000u);
    acc[6] += cf * __uint_as_float(v.w << 16);
    acc[7] += cf * __uint_as_float(v.w & 0xffff0000u);
  }
#pragma unroll
  for (int j = 0; j < 8; j++) {
    acc[j] += __shfl_xor(acc[j], 16);
    acc[j] += __shfl_xor(acc[j], 32);
  }
  if (g == 0) {
    float di = dinv[s * NN + node];
    float d2 = di * di;
    uint4 sv = *(const uint4*)(Y + (size_t)node * NH + fo);
    float4 b0 = *(const float4*)(p.bias[zi] + fo);
    float4 b1 = *(const float4*)(p.bias[zi] + fo + 4);
    float o0 = acc[0] + d2 * __uint_as_float(sv.x << 16) + b0.x;
    float o1 = acc[1] + d2 * __uint_as_float(sv.x & 0xffff0000u) + b0.y;
    float o2 = acc[2] + d2 * __uint_as_float(sv.y << 16) + b0.z;
    float o3 = acc[3] + d2 * __uint_as_float(sv.y & 0xffff0000u) + b0.w;
    float o4 = acc[4] + d2 * __uint_as_float(sv.z << 16) + b1.x;
    float o5 = acc[5] + d2 * __uint_as_float(sv.z & 0xffff0000u) + b1.y;
    float o6 = acc[6] + d2 * __uint_as_float(sv.w << 16) + b1.z;
    float o7 = acc[7] + d2 * __uint_as_float(sv.w & 0xffff0000u) + b1.w;
    uint4 ou;
    ou.x = f2bf(o0) | ((u32)f2bf(o1) << 16);
    ou.y = f2bf(o2) | ((u32)f2bf(o3) << 16);
    ou.z = f2bf(o4) | ((u32)f2bf(o5) << 16);
    ou.w = f2bf(o6) | ((u32)f2bf(o7) << 16);
    *(uint4*)(p.Xo[zi] + (size_t)node * NH + fo) = ou;
  }
}

// per-(chain,graph,feature) sum and sum-of-squares, flush-on-graph-change
__global__ __launch_bounds__(256) void k_stats(ZP p, const int* __restrict__ batch,
                                               float* __restrict__ ssum, float* __restrict__ ssq) {
  int zi = blockIdx.y;
  const u16* __restrict__ X = p.Xo[zi];
  int f = threadIdx.x & 127, rh = threadIdx.x >> 7;
  int r0 = blockIdx.x * 64;
  float s = 0.f, q = 0.f;
  int curg = -1;
  for (int i = rh; i < 64; i += 2) {
    int r = r0 + i;
    if (r >= NN) break;
    int g = batch[r];
    if (g != curg) {
      if (curg >= 0) {
        atomicAdd(&ssum[(zi * NG + curg) * NH + f], s);
        atomicAdd(&ssq[(zi * NG + curg) * NH + f], q);
      }
      curg = g; s = 0.f; q = 0.f;
    }
    float v = bf2f(X[(size_t)r * NH + f]);
    s += v;
    q += v * v;
  }
  if (curg >= 0) {
    atomicAdd(&ssum[(zi * NG + curg) * NH + f], s);
    atomicAdd(&ssq[(zi * NG + curg) * NH + f], q);
  }
}

// graph-norm + leaky relu -> bf16 Xn (next layer's A), accumulate per-graph sums into M[l]
__global__ __launch_bounds__(256) void k_apply(ZP p, const int* __restrict__ batch,
                                               const int* __restrict__ counts,
                                               const float* __restrict__ ssum,
                                               const float* __restrict__ ssq,
                                               float* __restrict__ Ml) {
  int zi = blockIdx.y;
  const u16* __restrict__ X = p.Xo[zi];
  u16* __restrict__ Xn = p.Xn[zi];
  int f = threadIdx.x & 127, rh = threadIdx.x >> 7;
  int r0 = blockIdx.x * 64;
  float w = p.gw[zi][f], b = p.gb[zi][f], ms = p.gms[zi][f];
  int col = p.colbase[zi] + f;
  float macc = 0.f;
  int curg = -1;
  float mean = 0.f, inv = 0.f;
  for (int i = rh; i < 64; i += 2) {
    int r = r0 + i;
    if (r >= NN) break;
    int g = batch[r];
    if (g != curg) {
      if (curg >= 0) atomicAdd(&Ml[curg * 640 + col], macc);
      macc = 0.f;
      curg = g;
      float cnt = fmaxf((float)counts[g], 1.f);
      float su = ssum[(zi * NG + g) * NH + f];
      float sq2 = ssq[(zi * NG + g) * NH + f];
      mean = su / cnt;
      float var = sq2 / cnt - (2.f * ms - ms * ms) * mean * mean;
      inv = rsqrtf(var + GEPS);
    }
    float v = bf2f(X[(size_t)r * NH + f]);
    float o = w * (v - ms * mean) * inv + b;
    o = (o >= 0.f) ? o : GSLOPE * o;
    Xn[(size_t)r * NH + f] = f2bf(o);
    macc += o;
  }
  if (curg >= 0) atomicAdd(&Ml[curg * 640 + col], macc);
}

// T[l][g][f] = M[l][g][:] @ mergeW[:,f]
__global__ __launch_bounds__(256) void k_merge(const float* __restrict__ M,
                                               const float* __restrict__ mergeW,
                                               float* __restrict__ T) {
  int g = blockIdx.x, l = blockIdx.y;
  int f = threadIdx.x & 127, h = threadIdx.x >> 7;
  __shared__ float mrow[640];
  __shared__ float red[128];
  const float* Mr = M + ((size_t)l * NG + g) * 640;
  for (int i = threadIdx.x; i < 640; i += 256) mrow[i] = Mr[i];
  __syncthreads();
  float s = 0.f;
  int k0 = h * 320;
#pragma unroll 8
  for (int k = k0; k < k0 + 320; k++) s += mrow[k] * mergeW[(size_t)k * NH + f];
  if (h) red[f] = s;
  __syncthreads();
  if (!h) T[((size_t)l * NG + g) * NH + f] = s + red[f];
}

__global__ __launch_bounds__(128) void k_out(const float* __restrict__ T,
                                             const float* __restrict__ mergeb,
                                             const int* __restrict__ counts,
                                             float* __restrict__ out) {
  int g = blockIdx.x, f = threadIdx.x;
  float cnt = fmaxf((float)counts[g], 1.f);
  float s = T[((size_t)0 * NG + g) * NH + f] + T[((size_t)1 * NG + g) * NH + f] +
            T[((size_t)2 * NG + g) * NH + f];
  out[(size_t)g * NH + f] = s / (3.f * cnt) + mergeb[f];
}

// ---------------- host ----------------

struct Offs {
  size_t counts, deg, M, T, stats, dinv, indptr, cursor, ent, wt, xbf, h0;
  size_t yb[NCH], xo[NCH], xn[NCH];
  size_t memset1_off, memset1_len, stats_len, total;
};

static size_t build_offs(Offs& o, int Etot) {
  size_t off = 0;
  auto alloc = [&](size_t bytes) -> size_t {
    off = (off + 255) & ~(size_t)255;
    size_t s = off;
    off += bytes;
    return s;
  };
  o.counts = alloc(NG * 4);
  o.deg = alloc((size_t)4 * NN * 4);
  o.M = alloc((size_t)NLAY * NG * 640 * 4);
  o.memset1_off = o.deg;
  o.memset1_len = (o.M + (size_t)NLAY * NG * 640 * 4) - o.deg;
  o.T = alloc((size_t)NLAY * NG * NH * 4);
  o.stats = alloc((size_t)2 * NCH * NG * NH * 4);
  o.stats_len = (size_t)2 * NCH * NG * NH * 4;
  o.dinv = alloc((size_t)4 * NN * 4);
  o.indptr = alloc((size_t)4 * (NN + 1) * 4);
  o.cursor = alloc((size_t)4 * (NN + 1) * 4);
  o.ent = alloc((size_t)Etot * 8);
  o.wt = alloc((size_t)7 * NH * NH * 2);
  o.xbf = alloc((size_t)NNP * NH * 2);
  o.h0 = alloc((size_t)NNP * NH * 2);
  for (int i = 0; i < NCH; i++) {
    o.yb[i] = alloc((size_t)NN * NH * 2);
    o.xo[i] = alloc((size_t)NN * NH * 2);
    o.xn[i] = alloc((size_t)NNP * NH * 2);
  }
  o.total = off;
  return off;
}

extern "C" void kernel_launch(void* const* d_in, const int* in_sizes, int n_in,
                              void* d_out, int out_size, void* d_ws, size_t ws_size,
                              hipStream_t stream) {
  if (n_in < 21) return;
  const float* x = (const float*)d_in[0];
  const float* embW = (const float*)d_in[1];
  const float* embb = (const float*)d_in[2];
  const float* mainW = (const float*)d_in[3];
  const float* mainb = (const float*)d_in[4];
  const float* maingw = (const float*)d_in[5];
  const float* maingb = (const float*)d_in[6];
  const float* maingms = (const float*)d_in[7];
  const float* locW = (const float*)d_in[8];
  const float* locb = (const float*)d_in[9];
  const float* locgw = (const float*)d_in[10];
  const float* locgb = (const float*)d_in[11];
  const float* locgms = (const float*)d_in[12];
  const float* mergeW = (const float*)d_in[13];
  const float* mergeb = (const float*)d_in[14];
  const int* edge_index = (const int*)d_in[15];
  // d_in[16] = edges0: permutation of edge_index under segment_sum -> reuse set 0
  const int* edges1 = (const int*)d_in[17];
  const int* edges2 = (const int*)d_in[18];
  const int* edges3 = (const int*)d_in[19];
  const int* batch = (const int*)d_in[20];

  int E0 = in_sizes[15] / 2;
  int E1 = in_sizes[17] / 2, E2 = in_sizes[18] / 2, E3 = in_sizes[19] / 2;
  int Etot = E0 + E1 + E2 + E3;
  int maxE = E0 > E1 ? E0 : E1;
  maxE = maxE > E2 ? maxE : E2;
  maxE = maxE > E3 ? maxE : E3;

  Offs o;
  if (build_offs(o, Etot) > ws_size) return;  // fail visibly

  char* ws = (char*)d_ws;
  int* counts = (int*)(ws + o.counts);
  int* deg = (int*)(ws + o.deg);
  float* M = (float*)(ws + o.M);
  float* T = (float*)(ws + o.T);
  float* ssum = (float*)(ws + o.stats);
  float* ssq = ssum + (size_t)NCH * NG * NH;
  float* dinv = (float*)(ws + o.dinv);
  int* indptr = (int*)(ws + o.indptr);
  int* cursor = (int*)(ws + o.cursor);
  int2* ent = (int2*)(ws + o.ent);
  u16* wt = (u16*)(ws + o.wt);
  u16* xbf = (u16*)(ws + o.xbf);
  u16* h0 = (u16*)(ws + o.h0);
  u16 *yb[NCH], *xo[NCH], *xn[NCH];
  for (int i = 0; i < NCH; i++) {
    yb[i] = (u16*)(ws + o.yb[i]);
    xo[i] = (u16*)(ws + o.xo[i]);
    xn[i] = (u16*)(ws + o.xn[i]);
  }

  ES4 es;
  es.e[0] = edge_index; es.e[1] = edges1; es.e[2] = edges2; es.e[3] = edges3;
  es.cnt[0] = E0; es.cnt[1] = E1; es.cnt[2] = E2; es.cnt[3] = E3;
  es.off[0] = 0; es.off[1] = E0; es.off[2] = E0 + E1; es.off[3] = E0 + E1 + E2;
  int4 entoff = make_int4(0, E0, E0 + E1, E0 + E1 + E2);

  hipMemsetAsync(ws + o.memset1_off, 0, o.memset1_len, stream);
  k_count<<<1, 64, 0, stream>>>(batch, counts);
  k_deg<<<dim3((maxE + 255) / 256, 4), 256, 0, stream>>>(es, deg);
  k_dinv<<<dim3((NN + 255) / 256, 4), 256, 0, stream>>>(deg, dinv);
  k_scan<<<4, 1024, 0, stream>>>(deg, indptr, cursor);
  k_fill<<<dim3((maxE + 255) / 256, 4), 256, 0, stream>>>(es, dinv, cursor, ent);
  k_prepw<<<dim3(NH, 7), NH, 0, stream>>>(embW, locW, mainW, wt);
  k_cast<<<(NN * NH / 8 + 255) / 256, 256, 0, stream>>>(x, xbf);

  const int nrb = (NN + 63) / 64;  // 313

  // embedding: h0 = x @ embW + embb (bf16)
  {
    ZP pe = {};
    pe.A[0] = xbf; pe.W[0] = wt; pe.Y[0] = h0;
    k_gemm_bf<<<dim3(nrb, 1), 256, 0, stream>>>(pe, embb);
  }

  for (int l = 0; l < NLAY; l++) {
    hipMemsetAsync(ws + o.stats, 0, o.stats_len, stream);
    ZP p = {};
    for (int zi = 0; zi < NCH; zi++) {
      bool isMain = (zi == 4);
      p.A[zi] = (l == 0) ? (const u16*)h0 : (const u16*)xn[zi];
      p.W[zi] = wt + (size_t)((isMain ? 4 : 1) + l) * NH * NH;
      p.Y[zi] = yb[zi];
      p.Xo[zi] = xo[zi];
      p.Xn[zi] = xn[zi];
      p.bias[zi] = (isMain ? mainb : locb) + (size_t)l * NH;
      p.gw[zi] = (isMain ? maingw : locgw) + (size_t)l * NH;
      p.gb[zi] = (isMain ? maingb : locgb) + (size_t)l * NH;
      p.gms[zi] = (isMain ? maingms : locgms) + (size_t)l * NH;
      p.set[zi] = (zi == 0 || zi == 4) ? 0 : zi;
      p.colbase[zi] = isMain ? 512 : zi * NH;
    }
    if (l == 0) {
      // chains 0..3 share A(h0) and W(locW[0]): compute once
      ZP pg = {};
      pg.A[0] = h0; pg.W[0] = wt + (size_t)1 * NH * NH; pg.Y[0] = yb[0];
      pg.A[1] = h0; pg.W[1] = wt + (size_t)4 * NH * NH; pg.Y[1] = yb[4];
      k_gemm_bf<<<dim3(nrb, 2), 256, 0, stream>>>(pg, (const float*)nullptr);
      p.Y[1] = yb[0]; p.Y[2] = yb[0]; p.Y[3] = yb[0];
    } else {
      k_gemm_bf<<<dim3(nrb, NCH), 256, 0, stream>>>(p, (const float*)nullptr);
    }
    k_agg<<<dim3(NN / 4, NCH), 256, 0, stream>>>(p, indptr, ent, dinv, entoff);
    k_stats<<<dim3(nrb, NCH), 256, 0, stream>>>(p, batch, ssum, ssq);
    k_apply<<<dim3(nrb, NCH), 256, 0, stream>>>(p, batch, counts, ssum, ssq,
                                                M + (size_t)l * NG * 640);
  }

  k_merge<<<dim3(NG, NLAY), 256, 0, stream>>>(M, mergeW, T);
  k_out<<<NG, 128, 0, stream>>>(T, mergeb, counts, (float*)d_out);
}